// Round 1
// 1101.873 us; speedup vs baseline: 1.2933x; 1.2933x over previous
//
#include <hip/hip_runtime.h>

#define NN 16
#define CC 192
#define TT 120
#define VV 100
#define NH 4

typedef __attribute__((ext_vector_type(4))) float  float4v;
typedef __attribute__((ext_vector_type(8))) short  short8;
typedef __attribute__((ext_vector_type(2))) int    int2v;

#define MFMA16(A,B,Cacc) __builtin_amdgcn_mfma_f32_16x16x32_bf16(A,B,Cacc,0,0,0)

union S8U { unsigned u[4]; short8 s; };

// truncating f32->bf16 pair pack: returns bf16(b)<<16 | bf16(a)  (1 v_perm)
__device__ __forceinline__ unsigned pk2(float a, float b) {
  union { float f; unsigned u; } x, y; x.f = a; y.f = b;
  return __builtin_amdgcn_perm(y.u, x.u, 0x07060302u);
}
__device__ __forceinline__ short b16t(float f) {
  union { float f; unsigned u; } x; x.f = f;
  return (short)(x.u >> 16);
}
// RNE (for one-time weight conversion)
__device__ __forceinline__ short f2b(float f) {
  union { float f; unsigned u; } x; x.f = f;
  unsigned r = x.u + 0x7fffu + ((x.u >> 16) & 1u);
  return (short)(r >> 16);
}

// ---------------- kernel 1: weights fp32 -> bf16, pre-swizzled into MFMA B-frag order ----------------
// frag layout: [tile][kc][lane(q*16+l15)][j]  <->  w[o=16*tile+l15][a=32*kc+8*q+j]
__global__ __launch_bounds__(256) void k_conv(const float* __restrict__ wq,
                                              const float* __restrict__ wk,
                                              const float* __restrict__ wp,
                                              short* __restrict__ wqF,
                                              short* __restrict__ wkF,
                                              short* __restrict__ wpF) {
  int i = blockIdx.x * 256 + threadIdx.x;   // grid 576 -> 147456
  if (i < CC*CC) {
    int o = i / CC, a = i % CC;
    int ct = o >> 4, l = o & 15, kc = a >> 5, q = (a & 31) >> 3, j = a & 7;
    int dst = ((ct*6 + kc)*64 + q*16 + l)*8 + j;
    wqF[dst] = f2b(wq[i]);
    wkF[dst] = f2b(wk[i]);
  }
  if (i < CC*CC*NH) {
    int o = i / (CC*NH), c2 = i % (CC*NH);
    int s = c2 / CC, cc = c2 % CC;
    int T = o >> 4, l = o & 15, kc = cc >> 5, q = (cc & 31) >> 3, j = cc & 7;
    int dst = (((s*12 + T)*6 + kc)*64 + q*16 + l)*8 + j;
    wpF[dst] = f2b(wp[i]);
  }
}

// ---------------- kernel 2: fused QK projection + scores ----------------
// grid 240 = (n, tc of 8 t's); 448 thr = 7 waves, wave w owns u-tile w.
__global__ __launch_bounds__(448, 2) void k_scoresB(const float* __restrict__ xq,
                                                    const float* __restrict__ xkv,
                                                    const short* __restrict__ wqF,
                                                    const short* __restrict__ wkF,
                                                    const float* __restrict__ bq,
                                                    const float* __restrict__ bk,
                                                    float* __restrict__ part) {
  __shared__ short QT[112*200];   // [u][o], stride 200
  __shared__ short KT[112*56];    // [v][c'], per-head, stride 56
  const int n = blockIdx.x / 15, tc = blockIdx.x % 15;
  const int tid = threadIdx.x, w = tid >> 6, lane = tid & 63;
  const int q = lane >> 4, l15 = lane & 15;
  const int u = 16*w + l15, uc = (u < VV) ? u : (VV-1);

  float4v acc[NH][7];
  #pragma unroll
  for (int s = 0; s < NH; ++s)
    #pragma unroll
    for (int vt = 0; vt < 7; ++vt) acc[s][vt] = (float4v){0.f,0.f,0.f,0.f};

  const short8 z8 = {0,0,0,0,0,0,0,0};

  #pragma unroll 1
  for (int it = 0; it < 8; ++it) {
    const int t = tc*8 + it;
    short8 xf[6];
    #pragma unroll
    for (int kc = 0; kc < 6; ++kc) {
      float f[8];
      #pragma unroll
      for (int j = 0; j < 8; ++j)
        f[j] = xq[(n*CC + 32*kc + 8*q + j)*(TT*VV) + t*VV + uc];
      S8U sv; sv.u[0]=pk2(f[0],f[1]); sv.u[1]=pk2(f[2],f[3]); sv.u[2]=pk2(f[4],f[5]); sv.u[3]=pk2(f[6],f[7]);
      xf[kc] = sv.s;
    }
    #pragma unroll
    for (int ct = 0; ct < 12; ++ct) {
      float4v d = (float4v){0.f,0.f,0.f,0.f};
      #pragma unroll
      for (int kc = 0; kc < 6; ++kc) {
        short8 wf = *(const short8*)&wqF[((ct*6 + kc)*64 + q*16 + l15)*8];
        d = MFMA16(xf[kc], wf, d);
      }
      float bb = bq[16*ct + l15];
      #pragma unroll
      for (int r = 0; r < 4; ++r)
        QT[(16*w + 4*q + r)*200 + 16*ct + l15] = b16t(d[r] + bb);
    }
    short8 xg[6];
    #pragma unroll
    for (int kc = 0; kc < 6; ++kc) {
      float f[8];
      #pragma unroll
      for (int j = 0; j < 8; ++j)
        f[j] = xkv[(n*CC + 32*kc + 8*q + j)*(TT*VV) + t*VV + uc];
      S8U sv; sv.u[0]=pk2(f[0],f[1]); sv.u[1]=pk2(f[2],f[3]); sv.u[2]=pk2(f[4],f[5]); sv.u[3]=pk2(f[6],f[7]);
      xg[kc] = sv.s;
    }
    #pragma unroll 1
    for (int s = 0; s < NH; ++s) {
      #pragma unroll
      for (int ctk = 0; ctk < 3; ++ctk) {
        float4v d = (float4v){0.f,0.f,0.f,0.f};
        #pragma unroll
        for (int kc = 0; kc < 6; ++kc) {
          short8 wf = *(const short8*)&wkF[(((3*s + ctk)*6 + kc)*64 + q*16 + l15)*8];
          d = MFMA16(xg[kc], wf, d);
        }
        float bb = bk[48*s + 16*ctk + l15];
        #pragma unroll
        for (int r = 0; r < 4; ++r)
          KT[(16*w + 4*q + r)*56 + 16*ctk + l15] = b16t(d[r] + bb);
      }
      __syncthreads();
      #pragma unroll
      for (int kcp = 0; kcp < 2; ++kcp) {
        short8 aQ = z8;
        if (kcp == 0 || q < 2)
          aQ = *(const short8*)&QT[(16*w + l15)*200 + 48*s + 32*kcp + 8*q];
        #pragma unroll
        for (int vt = 0; vt < 7; ++vt) {
          short8 bK = z8;
          if (kcp == 0 || q < 2)
            bK = *(const short8*)&KT[(16*vt + l15)*56 + 32*kcp + 8*q];
          acc[s][vt] = MFMA16(aQ, bK, acc[s][vt]);
        }
      }
      __syncthreads();
    }
  }
  // flush: part[n][tc][s][v][u112]; nontemporal (stream, read once by k_reduce)
  #pragma unroll
  for (int s = 0; s < NH; ++s)
    #pragma unroll
    for (int vt = 0; vt < 7; ++vt) {
      int v = 16*vt + l15;
      if (v < VV)
        __builtin_nontemporal_store(acc[s][vt],
          (float4v*)&part[(((n*15 + tc)*NH + s)*VV + v)*112 + 16*w + 4*q]);
    }
}

// ---------------- kernel 3: reduce + tanh + alpha/ga -> attnT bf16 [n][s][v112][u128] ----------------
__global__ __launch_bounds__(256) void k_reduce(const float* __restrict__ part,
                                                const float* __restrict__ alphas,
                                                const float* __restrict__ ga,
                                                short* __restrict__ attnT) {
  int bid = blockIdx.x;                 // 16*4*56 = 3584
  int n = bid / 224, rem = bid % 224, s = rem / 56, vc = rem % 56;
  int v = vc*2 + (threadIdx.x >> 7), uu = threadIdx.x & 127;
  float val = 0.f;
  if (v < VV && uu < VV) {
    float sum = 0.f;
    for (int tcc = 0; tcc < 15; ++tcc)
      sum += __builtin_nontemporal_load(&part[(((n*15 + tcc)*NH + s)*VV + v)*112 + uu]);
    val = tanhf(sum * (1.f/5760.f)) * alphas[s] + ga[uu*VV + v];
  }
  attnT[((n*NH + s)*112 + v)*128 + uu] = f2b(val);
}

// ---------------- kernel 4: values-first fused attn-apply + out-proj ----------------
// grid 1920 = (n,t); 256 thr = 4 waves; wave w owns c-tiles / o-tiles {w, w+4, w+8}.
// Phase B1 (per head s): Y_s[c][v] = sum_u X[c][u] * attn[u][v]
//   A = X natural [c][u] layout -> fragments load DIRECTLY from global (no transpose staging)
//   B = attnT[v][u] row-reads (u contiguous), reused across 3 c-tiles in registers
//   D: col v = l15, rows c = 16ct+4q+r  -> packed to LDS YT[v][c] (bf16)
// Phase B2: out[o][v] += sum_c wp[o][s*C+c] * Y_s[c][v]
//   A = YT rows v (k=c contiguous), B = wpF (pre-swizzled B-frags), D: col o, rows v.
__global__ __launch_bounds__(256, 2) void k_outC(const float* __restrict__ xkv,
                                                 const short* __restrict__ wpF,
                                                 const short* __restrict__ attnT,
                                                 const float* __restrict__ bp,
                                                 float* __restrict__ out) {
  __shared__ short YT[112*200];      // [v][c] bf16, stride 200, 44800 B
  const int n = blockIdx.x / TT, t = blockIdx.x % TT;
  const int tid = threadIdx.x, w = tid >> 6, lane = tid & 63;
  const int q = lane >> 4, l15 = lane & 15;

  float4v accO[3][7];
  #pragma unroll
  for (int i = 0; i < 3; ++i)
    #pragma unroll
    for (int vt = 0; vt < 7; ++vt) accO[i][vt] = (float4v){0.f,0.f,0.f,0.f};

  // global base for this lane's 3 c-rows of x_kv (row length VV=100 floats)
  const float* xb[3];
  #pragma unroll
  for (int i = 0; i < 3; ++i) {
    int c = 16*(w + 4*i) + l15;
    xb[i] = xkv + ((size_t)(n*CC + c)*TT + t)*VV;
  }

  #pragma unroll 1
  for (int s = 0; s < NH; ++s) {
    // ---- B1: Y accumulate over u (4 chunks of 32) ----
    float4v yacc[3][7];
    #pragma unroll
    for (int i = 0; i < 3; ++i)
      #pragma unroll
      for (int vt = 0; vt < 7; ++vt) yacc[i][vt] = (float4v){0.f,0.f,0.f,0.f};

    const short* aT = attnT + (size_t)((n*NH + s)*112)*128;

    #pragma unroll
    for (int ku = 0; ku < 4; ++ku) {
      short8 xa[3];
      #pragma unroll
      for (int i = 0; i < 3; ++i) {
        S8U sv;
        if (ku < 3) {
          const float4v A = *(const float4v*)(xb[i] + 32*ku + 8*q);
          const float4v B = *(const float4v*)(xb[i] + 32*ku + 8*q + 4);
          sv.u[0]=pk2(A[0],A[1]); sv.u[1]=pk2(A[2],A[3]);
          sv.u[2]=pk2(B[0],B[1]); sv.u[3]=pk2(B[2],B[3]);
        } else {
          // u = 96..127: only u=96..99 exist (attnT is zero for u>=100)
          if (q == 0) {
            const float4v A = *(const float4v*)(xb[i] + 96);
            sv.u[0]=pk2(A[0],A[1]); sv.u[1]=pk2(A[2],A[3]); sv.u[2]=0u; sv.u[3]=0u;
          } else {
            sv.u[0]=0u; sv.u[1]=0u; sv.u[2]=0u; sv.u[3]=0u;
          }
        }
        xa[i] = sv.s;
      }
      #pragma unroll
      for (int vt = 0; vt < 7; ++vt) {
        short8 bv = *(const short8*)&aT[(16*vt + l15)*128 + 32*ku + 8*q];
        #pragma unroll
        for (int i = 0; i < 3; ++i)
          yacc[i][vt] = MFMA16(xa[i], bv, yacc[i][vt]);
      }
    }

    // ---- Y -> LDS (bf16), D rows c=16ct+4q+r, col v=16vt+l15 ----
    __syncthreads();   // all waves done reading YT of previous head
    #pragma unroll
    for (int i = 0; i < 3; ++i)
      #pragma unroll
      for (int vt = 0; vt < 7; ++vt) {
        float4v d = yacc[i][vt];
        int2v pr; pr.x = (int)pk2(d[0], d[1]); pr.y = (int)pk2(d[2], d[3]);
        *(int2v*)&YT[(16*vt + l15)*200 + 16*(w + 4*i) + 4*q] = pr;
      }
    __syncthreads();   // YT(s) ready

    // ---- B2: out-proj, contract over c (6 chunks of 32) ----
    #pragma unroll
    for (int kc2 = 0; kc2 < 6; ++kc2) {
      short8 ya[7];
      #pragma unroll
      for (int vt = 0; vt < 7; ++vt)
        ya[vt] = *(const short8*)&YT[(16*vt + l15)*200 + 32*kc2 + 8*q];
      #pragma unroll
      for (int i = 0; i < 3; ++i) {
        short8 wf = *(const short8*)&wpF[(((s*12 + (w + 4*i))*6 + kc2)*64 + q*16 + l15)*8];
        #pragma unroll
        for (int vt = 0; vt < 7; ++vt)
          accO[i][vt] = MFMA16(ya[vt], wf, accO[i][vt]);
      }
    }
  }

  // epilogue: + bp, v-contiguous float4 nontemporal stores (streamed, no L2 pollution)
  #pragma unroll
  for (int i = 0; i < 3; ++i) {
    int o = 16*(w + 4*i) + l15;
    float b = bp[o];
    #pragma unroll
    for (int vt = 0; vt < 7; ++vt) {
      int v0 = 16*vt + 4*q;
      if (v0 < VV) {
        float4v r = accO[i][vt];
        r[0] += b; r[1] += b; r[2] += b; r[3] += b;
        __builtin_nontemporal_store(r, (float4v*)&out[((size_t)(n*CC + o)*TT + t)*VV + v0]);
      }
    }
  }
}

extern "C" void kernel_launch(void* const* d_in, const int* in_sizes, int n_in,
                              void* d_out, int out_size, void* d_ws, size_t ws_size,
                              hipStream_t stream) {
  const float* xq     = (const float*)d_in[0];
  const float* xkv    = (const float*)d_in[1];
  const float* wq     = (const float*)d_in[2];
  const float* bq     = (const float*)d_in[3];
  const float* wk     = (const float*)d_in[4];
  const float* bk     = (const float*)d_in[5];
  const float* wp     = (const float*)d_in[6];
  const float* bp     = (const float*)d_in[7];
  const float* alphas = (const float*)d_in[8];
  const float* ga     = (const float*)d_in[9];
  float* out = (float*)d_out;
  char*  ws  = (char*)d_ws;

  // ws: wqF 0..73728 | wkF ..147456 | wpF ..442368 | attnT ..2277376 | part ..45285376
  short* wqF   = (short*)(ws);
  short* wkF   = (short*)(ws + 73728);
  short* wpF   = (short*)(ws + 147456);
  short* attnT = (short*)(ws + 442368);
  float* part  = (float*)(ws + 2277376);

  hipLaunchKernelGGL(k_conv,    dim3(576),  dim3(256), 0, stream, wq, wk, wp, wqF, wkF, wpF);
  hipLaunchKernelGGL(k_scoresB, dim3(240),  dim3(448), 0, stream, xq, xkv, wqF, wkF, bq, bk, part);
  hipLaunchKernelGGL(k_reduce,  dim3(3584), dim3(256), 0, stream, part, alphas, ga, attnT);
  hipLaunchKernelGGL(k_outC,    dim3(1920), dim3(256), 0, stream, xkv, wpF, attnT, bp, out);
}

// Round 2
// 899.003 us; speedup vs baseline: 1.5852x; 1.2257x over previous
//
#include <hip/hip_runtime.h>

#define NN 16
#define CC 192
#define TT 120
#define VV 100
#define NH 4

typedef __attribute__((ext_vector_type(4))) float  float4v;
typedef __attribute__((ext_vector_type(8))) short  short8;
typedef __attribute__((ext_vector_type(2))) int    int2v;

#define MFMA16(A,B,Cacc) __builtin_amdgcn_mfma_f32_16x16x32_bf16(A,B,Cacc,0,0,0)

union S8U { unsigned u[4]; short8 s; };

// truncating f32->bf16 pair pack: returns bf16(b)<<16 | bf16(a)  (1 v_perm)
__device__ __forceinline__ unsigned pk2(float a, float b) {
  union { float f; unsigned u; } x, y; x.f = a; y.f = b;
  return __builtin_amdgcn_perm(y.u, x.u, 0x07060302u);
}
__device__ __forceinline__ short b16t(float f) {
  union { float f; unsigned u; } x; x.f = f;
  return (short)(x.u >> 16);
}
// RNE (for one-time weight conversion)
__device__ __forceinline__ short f2b(float f) {
  union { float f; unsigned u; } x; x.f = f;
  unsigned r = x.u + 0x7fffu + ((x.u >> 16) & 1u);
  return (short)(r >> 16);
}

// ---------------- kernel 1: weights fp32 -> bf16, pre-swizzled into MFMA frag order ----------------
// frag layout: [tile][kc][lane(q*16+l15)][j]  <->  w[o=16*tile+l15][a=32*kc+8*q+j]
__global__ __launch_bounds__(256) void k_conv(const float* __restrict__ wq,
                                              const float* __restrict__ wk,
                                              const float* __restrict__ wp,
                                              short* __restrict__ wqF,
                                              short* __restrict__ wkF,
                                              short* __restrict__ wpF) {
  int i = blockIdx.x * 256 + threadIdx.x;   // grid 576 -> 147456
  if (i < CC*CC) {
    int o = i / CC, a = i % CC;
    int ct = o >> 4, l = o & 15, kc = a >> 5, q = (a & 31) >> 3, j = a & 7;
    int dst = ((ct*6 + kc)*64 + q*16 + l)*8 + j;
    wqF[dst] = f2b(wq[i]);
    wkF[dst] = f2b(wk[i]);
  }
  if (i < CC*CC*NH) {
    int o = i / (CC*NH), c2 = i % (CC*NH);
    int s = c2 / CC, cc = c2 % CC;
    int T = o >> 4, l = o & 15, kc = cc >> 5, q = (cc & 31) >> 3, j = cc & 7;
    int dst = (((s*12 + T)*6 + kc)*64 + q*16 + l)*8 + j;
    wpF[dst] = f2b(wp[i]);
  }
}

// ---------------- kernel 2a: QK projection, output in scores-fragment order ----------------
// grid 1920 = (n,t); 448 thr = 7 waves; wave w owns u-tile ut=w. No LDS, no barriers.
// Out layout Qf/Kf[n][s][ut(7)][kk(180)][lane(64)][j(8)] bf16, k = 48*t + c' (c' within head).
// A-frag (weights, row=o) x B-frag (x, col=u) -> D[o-rows][u-cols]; scatter-pack D into frag slots.
__global__ __launch_bounds__(448, 2) void k_qk(const float* __restrict__ xq,
                                               const float* __restrict__ xkv,
                                               const short* __restrict__ wqF,
                                               const short* __restrict__ wkF,
                                               const float* __restrict__ bq,
                                               const float* __restrict__ bk,
                                               short* __restrict__ Qf,
                                               short* __restrict__ Kf) {
  const int n = blockIdx.x / TT, t = blockIdx.x % TT;
  const int tid = threadIdx.x, w = tid >> 6, lane = tid & 63;
  const int q = lane >> 4, l15 = lane & 15;
  const int u = 16*w + l15, uc = (u < VV) ? u : (VV-1);
  const size_t ns0 = (size_t)n*NH;

  #pragma unroll 1
  for (int ph = 0; ph < 2; ++ph) {
    const float* xb   = (ph ? xkv : xq) + (size_t)n*CC*TT*VV + t*VV;
    const short* wF   = ph ? wkF : wqF;
    const float* bias = ph ? bk : bq;
    short*       Of   = ph ? Kf : Qf;

    // B-frags of x: lane holds x[c=32kc+8q+j][u]
    short8 xf[6];
    #pragma unroll
    for (int kc = 0; kc < 6; ++kc) {
      float f[8];
      #pragma unroll
      for (int j = 0; j < 8; ++j)
        f[j] = xb[(size_t)(32*kc + 8*q + j)*(TT*VV) + uc];
      S8U sv; sv.u[0]=pk2(f[0],f[1]); sv.u[1]=pk2(f[2],f[3]); sv.u[2]=pk2(f[4],f[5]); sv.u[3]=pk2(f[6],f[7]);
      xf[kc] = sv.s;
    }
    #pragma unroll
    for (int ct = 0; ct < 12; ++ct) {
      float4v d = (float4v){0.f,0.f,0.f,0.f};
      #pragma unroll
      for (int kc = 0; kc < 6; ++kc) {
        short8 wf = *(const short8*)&wF[((ct*6 + kc)*64 + lane)*8];
        d = MFMA16(wf, xf[kc], d);   // D row = o = 16ct+4q+r, col = u = 16w+l15
      }
      const float4v bv = *(const float4v*)&bias[16*ct + 4*q];
      const int sH = ct/3;
      const int kb = 48*t + 16*(ct - 3*sH);      // k base for this ct (c' = 16*(ct%3)+4q+r)
      const int kq = kb + 4*q;                   // r in [0,4) stays within one (kk,q2)
      const int kk = kq >> 5, q2 = (kq >> 3) & 3, j2 = kq & 7;
      size_t base = ((((ns0 + sH)*7 + w)*180 + kk)*64 + (q2*16 + l15))*8 + j2;
      #pragma unroll
      for (int r = 0; r < 4; ++r)
        Of[base + r] = b16t(d[r] + bv[r]);
    }
  }
}

// ---------------- kernel 2b: scores GEMM over K=5760, fragment loads are 16B coalesced ----------------
// grid 384 = (n*4+s)*6 + kc-split; 448 thr = 7 waves; wave w owns u-tile ut=w, loops 7 v-tiles.
__global__ __launch_bounds__(448, 2) void k_scores2(const short* __restrict__ Qf,
                                                    const short* __restrict__ Kf,
                                                    float* __restrict__ part2) {
  const int b = blockIdx.x;
  const int kc = b % 6, ns = b / 6;
  const int tid = threadIdx.x, w = tid >> 6, lane = tid & 63;
  const int q = lane >> 4, l15 = lane & 15;
  const short* Qb = Qf + (((size_t)ns*7 + w)*180 + kc*30)*512 + lane*8;
  const short* Kb = Kf + ((size_t)ns*7*180 + kc*30)*512 + lane*8;

  float4v acc[7];
  #pragma unroll
  for (int vt = 0; vt < 7; ++vt) acc[vt] = (float4v){0.f,0.f,0.f,0.f};

  #pragma unroll 2
  for (int kk = 0; kk < 30; ++kk) {
    short8 aQ = *(const short8*)&Qb[(size_t)kk*512];
    #pragma unroll
    for (int vt = 0; vt < 7; ++vt) {
      short8 bK = *(const short8*)&Kb[((size_t)vt*180 + kk)*512];
      acc[vt] = MFMA16(aQ, bK, acc[vt]);   // D row = u = 16w+4q+r, col = v = 16vt+l15
    }
  }
  #pragma unroll
  for (int vt = 0; vt < 7; ++vt) {
    size_t p2 = (((size_t)ns*6 + kc)*112 + 16*vt + l15)*112 + 16*w + 4*q;
    __builtin_nontemporal_store(acc[vt], (float4v*)&part2[p2]);
  }
}

// ---------------- kernel 3: 6-way reduce + tanh + alpha/ga -> attnT bf16 [n][s][v112][u128] ----------------
__global__ __launch_bounds__(256) void k_reduce2(const float* __restrict__ part2,
                                                 const float* __restrict__ alphas,
                                                 const float* __restrict__ ga,
                                                 short* __restrict__ attnT) {
  int bid = blockIdx.x;                 // 64*56 = 3584
  int ns = bid / 56, vc = bid % 56;
  int v = vc*2 + (threadIdx.x >> 7), u = threadIdx.x & 127;
  int s = ns & 3;
  float val = 0.f;
  if (v < VV && u < VV) {
    float sum = 0.f;
    #pragma unroll
    for (int kc = 0; kc < 6; ++kc)
      sum += __builtin_nontemporal_load(&part2[(((size_t)ns*6 + kc)*112 + v)*112 + u]);
    val = tanhf(sum * (1.f/5760.f)) * alphas[s] + ga[u*VV + v];
  }
  attnT[((size_t)ns*112 + v)*128 + u] = f2b(val);
}

// ---------------- fallback kernels (old path) if workspace too small ----------------
__global__ __launch_bounds__(448, 2) void k_scoresB(const float* __restrict__ xq,
                                                    const float* __restrict__ xkv,
                                                    const short* __restrict__ wqF,
                                                    const short* __restrict__ wkF,
                                                    const float* __restrict__ bq,
                                                    const float* __restrict__ bk,
                                                    float* __restrict__ part) {
  __shared__ short QT[112*200];
  __shared__ short KT[112*56];
  const int n = blockIdx.x / 15, tc = blockIdx.x % 15;
  const int tid = threadIdx.x, w = tid >> 6, lane = tid & 63;
  const int q = lane >> 4, l15 = lane & 15;
  const int u = 16*w + l15, uc = (u < VV) ? u : (VV-1);
  float4v acc[NH][7];
  #pragma unroll
  for (int s = 0; s < NH; ++s)
    #pragma unroll
    for (int vt = 0; vt < 7; ++vt) acc[s][vt] = (float4v){0.f,0.f,0.f,0.f};
  const short8 z8 = {0,0,0,0,0,0,0,0};
  #pragma unroll 1
  for (int it = 0; it < 8; ++it) {
    const int t = tc*8 + it;
    short8 xf[6];
    #pragma unroll
    for (int kc = 0; kc < 6; ++kc) {
      float f[8];
      #pragma unroll
      for (int j = 0; j < 8; ++j)
        f[j] = xq[(n*CC + 32*kc + 8*q + j)*(TT*VV) + t*VV + uc];
      S8U sv; sv.u[0]=pk2(f[0],f[1]); sv.u[1]=pk2(f[2],f[3]); sv.u[2]=pk2(f[4],f[5]); sv.u[3]=pk2(f[6],f[7]);
      xf[kc] = sv.s;
    }
    #pragma unroll
    for (int ct = 0; ct < 12; ++ct) {
      float4v d = (float4v){0.f,0.f,0.f,0.f};
      #pragma unroll
      for (int kc = 0; kc < 6; ++kc) {
        short8 wf = *(const short8*)&wqF[((ct*6 + kc)*64 + q*16 + l15)*8];
        d = MFMA16(xf[kc], wf, d);
      }
      float bb = bq[16*ct + l15];
      #pragma unroll
      for (int r = 0; r < 4; ++r)
        QT[(16*w + 4*q + r)*200 + 16*ct + l15] = b16t(d[r] + bb);
    }
    short8 xg[6];
    #pragma unroll
    for (int kc = 0; kc < 6; ++kc) {
      float f[8];
      #pragma unroll
      for (int j = 0; j < 8; ++j)
        f[j] = xkv[(n*CC + 32*kc + 8*q + j)*(TT*VV) + t*VV + uc];
      S8U sv; sv.u[0]=pk2(f[0],f[1]); sv.u[1]=pk2(f[2],f[3]); sv.u[2]=pk2(f[4],f[5]); sv.u[3]=pk2(f[6],f[7]);
      xg[kc] = sv.s;
    }
    #pragma unroll 1
    for (int s = 0; s < NH; ++s) {
      #pragma unroll
      for (int ctk = 0; ctk < 3; ++ctk) {
        float4v d = (float4v){0.f,0.f,0.f,0.f};
        #pragma unroll
        for (int kc = 0; kc < 6; ++kc) {
          short8 wf = *(const short8*)&wkF[(((3*s + ctk)*6 + kc)*64 + q*16 + l15)*8];
          d = MFMA16(xg[kc], wf, d);
        }
        float bb = bk[48*s + 16*ctk + l15];
        #pragma unroll
        for (int r = 0; r < 4; ++r)
          KT[(16*w + 4*q + r)*56 + 16*ctk + l15] = b16t(d[r] + bb);
      }
      __syncthreads();
      #pragma unroll
      for (int kcp = 0; kcp < 2; ++kcp) {
        short8 aQ = z8;
        if (kcp == 0 || q < 2)
          aQ = *(const short8*)&QT[(16*w + l15)*200 + 48*s + 32*kcp + 8*q];
        #pragma unroll
        for (int vt = 0; vt < 7; ++vt) {
          short8 bK = z8;
          if (kcp == 0 || q < 2)
            bK = *(const short8*)&KT[(16*vt + l15)*56 + 32*kcp + 8*q];
          acc[s][vt] = MFMA16(aQ, bK, acc[s][vt]);
        }
      }
      __syncthreads();
    }
  }
  #pragma unroll
  for (int s = 0; s < NH; ++s)
    #pragma unroll
    for (int vt = 0; vt < 7; ++vt) {
      int v = 16*vt + l15;
      if (v < VV)
        __builtin_nontemporal_store(acc[s][vt],
          (float4v*)&part[(((n*15 + tc)*NH + s)*VV + v)*112 + 16*w + 4*q]);
    }
}

__global__ __launch_bounds__(256) void k_reduce(const float* __restrict__ part,
                                                const float* __restrict__ alphas,
                                                const float* __restrict__ ga,
                                                short* __restrict__ attnT) {
  int bid = blockIdx.x;
  int n = bid / 224, rem = bid % 224, s = rem / 56, vc = rem % 56;
  int v = vc*2 + (threadIdx.x >> 7), uu = threadIdx.x & 127;
  float val = 0.f;
  if (v < VV && uu < VV) {
    float sum = 0.f;
    for (int tcc = 0; tcc < 15; ++tcc)
      sum += __builtin_nontemporal_load(&part[(((n*15 + tcc)*NH + s)*VV + v)*112 + uu]);
    val = tanhf(sum * (1.f/5760.f)) * alphas[s] + ga[uu*VV + v];
  }
  attnT[((n*NH + s)*112 + v)*128 + uu] = f2b(val);
}

// ---------------- kernel 4: values-first fused attn-apply + out-proj ----------------
__global__ __launch_bounds__(256, 2) void k_outC(const float* __restrict__ xkv,
                                                 const short* __restrict__ wpF,
                                                 const short* __restrict__ attnT,
                                                 const float* __restrict__ bp,
                                                 float* __restrict__ out) {
  __shared__ short YT[112*200];      // [v][c] bf16, stride 200, 44800 B
  const int n = blockIdx.x / TT, t = blockIdx.x % TT;
  const int tid = threadIdx.x, w = tid >> 6, lane = tid & 63;
  const int q = lane >> 4, l15 = lane & 15;

  float4v accO[3][7];
  #pragma unroll
  for (int i = 0; i < 3; ++i)
    #pragma unroll
    for (int vt = 0; vt < 7; ++vt) accO[i][vt] = (float4v){0.f,0.f,0.f,0.f};

  const float* xb[3];
  #pragma unroll
  for (int i = 0; i < 3; ++i) {
    int c = 16*(w + 4*i) + l15;
    xb[i] = xkv + ((size_t)(n*CC + c)*TT + t)*VV;
  }

  #pragma unroll 1
  for (int s = 0; s < NH; ++s) {
    float4v yacc[3][7];
    #pragma unroll
    for (int i = 0; i < 3; ++i)
      #pragma unroll
      for (int vt = 0; vt < 7; ++vt) yacc[i][vt] = (float4v){0.f,0.f,0.f,0.f};

    const short* aT = attnT + (size_t)((n*NH + s)*112)*128;

    #pragma unroll
    for (int ku = 0; ku < 4; ++ku) {
      short8 xa[3];
      #pragma unroll
      for (int i = 0; i < 3; ++i) {
        S8U sv;
        if (ku < 3) {
          const float4v A = *(const float4v*)(xb[i] + 32*ku + 8*q);
          const float4v B = *(const float4v*)(xb[i] + 32*ku + 8*q + 4);
          sv.u[0]=pk2(A[0],A[1]); sv.u[1]=pk2(A[2],A[3]);
          sv.u[2]=pk2(B[0],B[1]); sv.u[3]=pk2(B[2],B[3]);
        } else {
          if (q == 0) {
            const float4v A = *(const float4v*)(xb[i] + 96);
            sv.u[0]=pk2(A[0],A[1]); sv.u[1]=pk2(A[2],A[3]); sv.u[2]=0u; sv.u[3]=0u;
          } else {
            sv.u[0]=0u; sv.u[1]=0u; sv.u[2]=0u; sv.u[3]=0u;
          }
        }
        xa[i] = sv.s;
      }
      #pragma unroll
      for (int vt = 0; vt < 7; ++vt) {
        short8 bv = *(const short8*)&aT[(16*vt + l15)*128 + 32*ku + 8*q];
        #pragma unroll
        for (int i = 0; i < 3; ++i)
          yacc[i][vt] = MFMA16(xa[i], bv, yacc[i][vt]);
      }
    }

    __syncthreads();
    #pragma unroll
    for (int i = 0; i < 3; ++i)
      #pragma unroll
      for (int vt = 0; vt < 7; ++vt) {
        float4v d = yacc[i][vt];
        int2v pr; pr.x = (int)pk2(d[0], d[1]); pr.y = (int)pk2(d[2], d[3]);
        *(int2v*)&YT[(16*vt + l15)*200 + 16*(w + 4*i) + 4*q] = pr;
      }
    __syncthreads();

    #pragma unroll
    for (int kc2 = 0; kc2 < 6; ++kc2) {
      short8 ya[7];
      #pragma unroll
      for (int vt = 0; vt < 7; ++vt)
        ya[vt] = *(const short8*)&YT[(16*vt + l15)*200 + 32*kc2 + 8*q];
      #pragma unroll
      for (int i = 0; i < 3; ++i) {
        short8 wf = *(const short8*)&wpF[(((s*12 + (w + 4*i))*6 + kc2)*64 + q*16 + l15)*8];
        #pragma unroll
        for (int vt = 0; vt < 7; ++vt)
          accO[i][vt] = MFMA16(ya[vt], wf, accO[i][vt]);
      }
    }
  }

  #pragma unroll
  for (int i = 0; i < 3; ++i) {
    int o = 16*(w + 4*i) + l15;
    float b = bp[o];
    #pragma unroll
    for (int vt = 0; vt < 7; ++vt) {
      int v0 = 16*vt + 4*q;
      if (v0 < VV) {
        float4v r = accO[i][vt];
        r[0] += b; r[1] += b; r[2] += b; r[3] += b;
        __builtin_nontemporal_store(r, (float4v*)&out[((size_t)(n*CC + o)*TT + t)*VV + v0]);
      }
    }
  }
}

extern "C" void kernel_launch(void* const* d_in, const int* in_sizes, int n_in,
                              void* d_out, int out_size, void* d_ws, size_t ws_size,
                              hipStream_t stream) {
  const float* xq     = (const float*)d_in[0];
  const float* xkv    = (const float*)d_in[1];
  const float* wq     = (const float*)d_in[2];
  const float* bq     = (const float*)d_in[3];
  const float* wk     = (const float*)d_in[4];
  const float* bk     = (const float*)d_in[5];
  const float* wp     = (const float*)d_in[6];
  const float* bp     = (const float*)d_in[7];
  const float* alphas = (const float*)d_in[8];
  const float* ga     = (const float*)d_in[9];
  float* out = (float*)d_out;
  char*  ws  = (char*)d_ws;

  // ws layout (new path):
  // wqF 0..73728 | wkF ..147456 | wpF ..442368 | attnT ..2277376 |
  // Qf ..84852736 | Kf ..167428096 | part2 ..186695680
  short* wqF   = (short*)(ws);
  short* wkF   = (short*)(ws + 73728);
  short* wpF   = (short*)(ws + 147456);
  short* attnT = (short*)(ws + 442368);

  hipLaunchKernelGGL(k_conv, dim3(576), dim3(256), 0, stream, wq, wk, wp, wqF, wkF, wpF);

  if (ws_size >= 186695680ULL) {
    short* Qf    = (short*)(ws + 2277376);
    short* Kf    = (short*)(ws + 84852736ULL);
    float* part2 = (float*)(ws + 167428096ULL);
    hipLaunchKernelGGL(k_qk,      dim3(1920), dim3(448), 0, stream, xq, xkv, wqF, wkF, bq, bk, Qf, Kf);
    hipLaunchKernelGGL(k_scores2, dim3(384),  dim3(448), 0, stream, Qf, Kf, part2);
    hipLaunchKernelGGL(k_reduce2, dim3(3584), dim3(256), 0, stream, part2, alphas, ga, attnT);
  } else {
    float* part = (float*)(ws + 2277376);
    hipLaunchKernelGGL(k_scoresB, dim3(240),  dim3(448), 0, stream, xq, xkv, wqF, wkF, bq, bk, part);
    hipLaunchKernelGGL(k_reduce,  dim3(3584), dim3(256), 0, stream, part, alphas, ga, attnT);
  }

  hipLaunchKernelGGL(k_outC, dim3(1920), dim3(256), 0, stream, xkv, wpF, attnT, bp, out);
}